// Round 1
// 2208.158 us; speedup vs baseline: 1.3604x; 1.3604x over previous
//
#include <hip/hip_runtime.h>

// ---------------------------------------------------------------------------
// PRGAT fused transformer block on MI355X (gfx950), bf16 MFMA pipeline.
//
// Math restructuring (exact up to bf16 rounding):
//   G    = Wq @ Wk^T                    (512x512)
//   s[b,n,m] = x_n G x_m^T + x_n.(Wq bk) + (Wk bq).x_m + bq.bk
//   attn = softmax(leaky_relu(s/scale))
//   Wvo  = Wv @ Wo ; bvo = bv @ Wo
//   out  = attn @ (x@Wvo + bvo) + bo
//   h    = LN(x + out; g1,be1)                      [stored bf16 in ws]
//   hid  = relu(h@Wf1+bf1)                          [bf16, aliased in refined]
//   refined = LN(h + hid@Wf2 + bf2; g2,be2)         [fp32 to d_out]
//   score = relu(refined@Ws1+bs1)@ws2 + bs2 ; alpha = softmax_n
//   fused = LN_paramfree(sum_n alpha_n * refined_n)
// ---------------------------------------------------------------------------

typedef __attribute__((ext_vector_type(8))) short s8v;   // 8 x bf16 (4 VGPRs)
typedef __attribute__((ext_vector_type(4))) float f4v;   // MFMA accum

#define MFMA16 __builtin_amdgcn_mfma_f32_16x16x32_bf16

__device__ __forceinline__ unsigned short f2bf(float f) {
  union { float f; unsigned u; } v; v.f = f;
  unsigned u = v.u;
  unsigned r = (u + 0x7FFFu + ((u >> 16) & 1u)) >> 16;   // RNE
  return (unsigned short)r;
}
__device__ __forceinline__ float bf2f(unsigned short h) {
  union { unsigned u; float f; } v; v.u = ((unsigned)h) << 16;
  return v.f;
}

// async global->LDS, 16B per lane; lds dest = wave-uniform base + lane*16
__device__ __forceinline__ void gload_lds16(const void* g, void* l) {
  __builtin_amdgcn_global_load_lds(
      (const __attribute__((address_space(1))) unsigned int*)g,
      (__attribute__((address_space(3))) unsigned int*)l, 16, 0, 0);
}

// Stage 64 rows x 512 cols of fp32 -> bf16 into padded LDS [64][520].
#define STAGE64_F32(SRC) do { \
    const float4* sp_ = (const float4*)(SRC); \
    _Pragma("unroll") \
    for (int p_ = 0; p_ < 16; ++p_) { \
      int idx_ = p_ * 512 + tid; \
      int r_ = idx_ >> 7, c_ = (idx_ & 127) << 2; \
      float4 v_ = sp_[idx_]; \
      uint2 w_; \
      w_.x = (unsigned)f2bf(v_.x) | ((unsigned)f2bf(v_.y) << 16); \
      w_.y = (unsigned)f2bf(v_.z) | ((unsigned)f2bf(v_.w) << 16); \
      *(uint2*)(xs + r_ * 520 + c_) = w_; \
    } } while (0)

// K-loop: 64 rows x 512 cols, K=512, A in LDS xs[64][520], B bf16 [n][LDB].
// Wave w: rw=w>>2 picks 32-row half, cw=w&3 picks 128-col quarter.
#define KLOOP_512(BT, LDB) do { \
    const int ar0_ = (rw * 32 + l15) * 520, ar1_ = (rw * 32 + 16 + l15) * 520; \
    for (int ks_ = 0; ks_ < 16; ++ks_) { \
      int k0_ = ks_ * 32 + quad * 8; \
      s8v a0_ = *(const s8v*)(xs + ar0_ + k0_); \
      s8v a1_ = *(const s8v*)(xs + ar1_ + k0_); \
      _Pragma("unroll") \
      for (int ct_ = 0; ct_ < 8; ++ct_) { \
        int n_ = cw * 128 + ct_ * 16 + l15; \
        s8v b_ = *(const s8v*)((BT) + n_ * (LDB) + k0_); \
        acc[0][ct_] = MFMA16(a0_, b_, acc[0][ct_], 0, 0, 0); \
        acc[1][ct_] = MFMA16(a1_, b_, acc[1][ct_], 0, 0, 0); \
      } \
    } } while (0)

// ---------------------------------------------------------------------------
// Prep kernels (run every launch; ws is re-poisoned by harness)
// ---------------------------------------------------------------------------

// out[d*512+j] = in[j*512+d]  (fp32 512x512 transpose)
__global__ void tr32(const float* __restrict__ in, float* __restrict__ out) {
  int idx = blockIdx.x * 256 + threadIdx.x;
  int d = idx >> 9, j = idx & 511;
  out[idx] = in[j * 512 + d];
}

// C_bf16[i*512+j] = sum_d A[i*512+d] * B[j*512+d]   (512x512x512, NT)
__global__ void nt_small(const float* __restrict__ A, const float* __restrict__ B,
                         unsigned short* __restrict__ C) {
  __shared__ float As[64][68], Bs[64][68];
  int tx = threadIdx.x & 15, ty = threadIdx.x >> 4;
  int i0 = blockIdx.x * 64, j0 = blockIdx.y * 64;
  float acc[4][4] = {};
  for (int d0 = 0; d0 < 512; d0 += 64) {
    #pragma unroll
    for (int p = 0; p < 4; ++p) {
      int idx = p * 256 + threadIdx.x;       // 1024 float4 units
      int r = idx >> 4, c = (idx & 15) << 2;
      *(float4*)&As[r][c] = *(const float4*)&A[(i0 + r) * 512 + d0 + c];
      *(float4*)&Bs[r][c] = *(const float4*)&B[(j0 + r) * 512 + d0 + c];
    }
    __syncthreads();
    for (int dd = 0; dd < 64; ++dd) {
      float ar[4], br[4];
      #pragma unroll
      for (int r = 0; r < 4; ++r) ar[r] = As[ty * 4 + r][dd];
      #pragma unroll
      for (int c = 0; c < 4; ++c) br[c] = Bs[tx * 4 + c][dd];
      #pragma unroll
      for (int r = 0; r < 4; ++r)
        #pragma unroll
        for (int c = 0; c < 4; ++c) acc[r][c] += ar[r] * br[c];
    }
    __syncthreads();
  }
  #pragma unroll
  for (int r = 0; r < 4; ++r)
    #pragma unroll
    for (int c = 0; c < 4; ++c)
      C[(i0 + ty * 4 + r) * 512 + j0 + tx * 4 + c] = f2bf(acc[r][c]);
}

// out_bf16[n*K+k] = in[k*N+n]  (transpose + convert)
__global__ void trcvt(const float* __restrict__ in, unsigned short* __restrict__ out,
                      int K, int N) {
  int idx = blockIdx.x * 256 + threadIdx.x;
  if (idx >= K * N) return;
  int n = idx / K, k = idx - n * K;
  out[idx] = f2bf(in[(size_t)k * N + n]);
}

// u[i]=Wq[i,:].bk  w[j]=Wk[j,:].bq  bvo[d]=sum_j bv[j]Wo[j,d]  c=bq.bk
__global__ void vecprep(const float* __restrict__ wq, const float* __restrict__ wk,
                        const float* __restrict__ wo, const float* __restrict__ bq,
                        const float* __restrict__ bk, const float* __restrict__ bv,
                        float* __restrict__ uvec, float* __restrict__ wvec,
                        float* __restrict__ cvec, float* __restrict__ bvo) {
  int t = threadIdx.x;
  if (blockIdx.x == 0) {
    float s = 0.f; for (int d = 0; d < 512; ++d) s += wq[t * 512 + d] * bk[d];
    uvec[t] = s;
  } else if (blockIdx.x == 1) {
    float s = 0.f; for (int d = 0; d < 512; ++d) s += wk[t * 512 + d] * bq[d];
    wvec[t] = s;
  } else if (blockIdx.x == 2) {
    float s = 0.f; for (int j = 0; j < 512; ++j) s += bv[j] * wo[j * 512 + t];
    bvo[t] = s;
  } else {
    __shared__ float red[512];
    red[t] = bq[t] * bk[t];
    __syncthreads();
    for (int o = 256; o; o >>= 1) { if (t < o) red[t] += red[t + o]; __syncthreads(); }
    if (t == 0) cvec[0] = red[0];
  }
}

// ---------------------------------------------------------------------------
// K1: z = x @ G^T (never stored); epilogue computes attention weights.
// ---------------------------------------------------------------------------
__global__ __launch_bounds__(512, 2) void k1_attn(
    const float* __restrict__ x, const unsigned short* __restrict__ gqk,
    const float* __restrict__ uvec, const float* __restrict__ wvec,
    const float* __restrict__ cvec, float* __restrict__ attn) {
  __shared__ unsigned short xs[64 * 520];
  __shared__ float sbuf[32][2][2];
  __shared__ float rru[64];
  __shared__ float rrw[64];
  const int tid = threadIdx.x;
  const int wave = tid >> 6, lane = tid & 63, quad = lane >> 4, l15 = lane & 15;
  const int rw = wave >> 2, cw = wave & 3;
  const size_t row0 = (size_t)blockIdx.x * 64;

  if (tid < 128) ((float*)sbuf)[tid] = 0.f;
  else if (tid < 192) rru[tid - 128] = 0.f;
  else if (tid < 256) rrw[tid - 192] = 0.f;

  STAGE64_F32(x + row0 * 512);
  __syncthreads();

  // per-row bias dots: rru[r]=u.x_r  rrw[r]=w.x_r  (8 threads per row)
  {
    int row = tid >> 3, cb = (tid & 7) * 64;
    float su = 0.f, sw = 0.f;
    for (int c2 = 0; c2 < 64; ++c2) {
      float xv = bf2f(xs[row * 520 + cb + c2]);
      su += xv * uvec[cb + c2];
      sw += xv * wvec[cb + c2];
    }
    atomicAdd(&rru[row], su);
    atomicAdd(&rrw[row], sw);
  }

  f4v acc[2][8] = {};
  KLOOP_512(gqk, 512);

  // partial dots s[b,n,m] += x[2b+n,col] * z[2b+m,col] over this lane's cols
  float part[2][4][2] = {};
  #pragma unroll
  for (int t = 0; t < 2; ++t) {
    #pragma unroll
    for (int ct = 0; ct < 8; ++ct) {
      int col = cw * 128 + ct * 16 + l15;
      #pragma unroll
      for (int g = 0; g < 4; ++g) {
        int m = rw * 32 + t * 16 + quad * 4 + g;
        float zv = acc[t][ct][g];
        int b2 = m & ~1;
        part[t][g][0] += bf2f(xs[b2 * 520 + col]) * zv;
        part[t][g][1] += bf2f(xs[(b2 + 1) * 520 + col]) * zv;
      }
    }
  }
  #pragma unroll
  for (int t = 0; t < 2; ++t)
    #pragma unroll
    for (int g = 0; g < 4; ++g) {
      int m = rw * 32 + t * 16 + quad * 4 + g;
      atomicAdd(&sbuf[m >> 1][0][m & 1], part[t][g][0]);
      atomicAdd(&sbuf[m >> 1][1][m & 1], part[t][g][1]);
    }
  __syncthreads();

  if (tid < 64) {
    int bl = tid >> 1, nn = tid & 1;
    float cc = cvec[0];
    float ru = rru[bl * 2 + nn];
    float scale = sqrtf(512.f) + 1e-8f;
    float s0 = (sbuf[bl][nn][0] + ru + rrw[bl * 2 + 0] + cc) / scale;
    float s1 = (sbuf[bl][nn][1] + ru + rrw[bl * 2 + 1] + cc) / scale;
    s0 = s0 > 0.f ? s0 : 0.2f * s0;
    s1 = s1 > 0.f ? s1 : 0.2f * s1;
    float mx = fmaxf(s0, s1);
    float e0 = expf(s0 - mx), e1 = expf(s1 - mx);
    float inv = 1.f / (e0 + e1);
    size_t gb = (size_t)blockIdx.x * 32 + bl;
    attn[gb * 4 + nn * 2 + 0] = e0 * inv;
    attn[gb * 4 + nn * 2 + 1] = e1 * inv;
  }
}

// ---------------------------------------------------------------------------
// K2: vo = x@Wvo + bvo ; out = attn-mix(vo) + bo ; h = LN(x+out)  -> h bf16
// ---------------------------------------------------------------------------
__global__ __launch_bounds__(512, 2) void k2_proj(
    const float* __restrict__ x, const unsigned short* __restrict__ wvoT,
    const float* __restrict__ bvo, const float* __restrict__ bo,
    const float* __restrict__ attn, const float* __restrict__ g1,
    const float* __restrict__ be1, unsigned short* __restrict__ hout) {
  __shared__ unsigned short xs[64 * 520];
  __shared__ unsigned short vos[64 * 520];
  const int tid = threadIdx.x;
  const int wave = tid >> 6, lane = tid & 63, quad = lane >> 4, l15 = lane & 15;
  const int rw = wave >> 2, cw = wave & 3;
  const size_t row0 = (size_t)blockIdx.x * 64;

  STAGE64_F32(x + row0 * 512);
  __syncthreads();

  f4v acc[2][8] = {};
  KLOOP_512(wvoT, 512);

  #pragma unroll
  for (int t = 0; t < 2; ++t)
    #pragma unroll
    for (int ct = 0; ct < 8; ++ct) {
      int col = cw * 128 + ct * 16 + l15;
      float bb = bvo[col];
      #pragma unroll
      for (int g = 0; g < 4; ++g) {
        int m = rw * 32 + t * 16 + quad * 4 + g;
        vos[m * 520 + col] = f2bf(acc[t][ct][g] + bb);
      }
    }
  __syncthreads();

  for (int rr = 0; rr < 8; ++rr) {
    int r = wave * 8 + rr;
    size_t grow = row0 + r;
    size_t gb = (size_t)blockIdx.x * 32 + (r >> 1);
    float a0 = attn[gb * 4 + (r & 1) * 2 + 0];
    float a1 = attn[gb * 4 + (r & 1) * 2 + 1];
    int c0 = lane * 8;
    int b2 = r & ~1;
    float v[8]; float s = 0.f, s2 = 0.f;
    #pragma unroll
    for (int j = 0; j < 8; ++j) {
      int c = c0 + j;
      float val = bf2f(xs[r * 520 + c]) + a0 * bf2f(vos[b2 * 520 + c]) +
                  a1 * bf2f(vos[(b2 + 1) * 520 + c]) + bo[c];
      v[j] = val; s += val; s2 += val * val;
    }
    #pragma unroll
    for (int o = 32; o; o >>= 1) { s += __shfl_xor(s, o); s2 += __shfl_xor(s2, o); }
    float mu = s * (1.f / 512.f);
    float var = s2 * (1.f / 512.f) - mu * mu;
    float rs = rsqrtf(var + 1e-5f);
    unsigned short o8[8];
    #pragma unroll
    for (int j = 0; j < 8; ++j)
      o8[j] = f2bf((v[j] - mu) * rs * g1[c0 + j] + be1[c0 + j]);
    int4 w4;
    w4.x = (int)((unsigned)o8[0] | ((unsigned)o8[1] << 16));
    w4.y = (int)((unsigned)o8[2] | ((unsigned)o8[3] << 16));
    w4.z = (int)((unsigned)o8[4] | ((unsigned)o8[5] << 16));
    w4.w = (int)((unsigned)o8[6] | ((unsigned)o8[7] << 16));
    *(int4*)(hout + grow * 512 + c0) = w4;
  }
}

// ---------------------------------------------------------------------------
// K3a: hid = relu(h @ Wf1 + bf1)  (bf16, stored into the refined buffer)
// m97-style staged GEMM: 64x512 tile, BK=64, global_load_lds + XOR swizzle.
// Block: 512 thr (8 waves, 2x4). Wave tile 32x128. LDS 72.5 KB -> 2 blk/CU.
// ---------------------------------------------------------------------------
__global__ __launch_bounds__(512, 4) void k3a_ffn1(
    const unsigned short* __restrict__ h, const unsigned short* __restrict__ wf1T,
    const float* __restrict__ bf1, unsigned short* __restrict__ hid) {
  __shared__ unsigned short As[64 * 64];   // 8 KB  [r][64k], 16B slots XOR-swizzled
  __shared__ unsigned short Bs[512 * 64];  // 64 KB [n][64k], swizzled
  const int tid = threadIdx.x;
  const int wave = tid >> 6, lane = tid & 63, quad = lane >> 4, l15 = lane & 15;
  const int rw = wave >> 2, cw = wave & 3;
  const size_t row0 = (size_t)blockIdx.x * 64;
  const int n0 = blockIdx.y * 512;

  // A staging coords: thread -> (row ar, swizzled 16B slot ao) ; dest is linear
  const int ar = tid >> 3;
  const int ao = (tid & 7) ^ (ar & 7);
  const char* asrc = (const char*)(h + (row0 + ar) * 512) + ao * 16;
  char* adst = (char*)As + (size_t)wave * 1024;

  const int aswz = (l15 & 7);              // row-dependent read swizzle
  const int abase0 = (rw * 32 + l15) * 128;
  const int abase1 = (rw * 32 + 16 + l15) * 128;
  const int bbase = (cw * 128 + l15) * 128;

  f4v acc[2][8] = {};
  for (int ks = 0; ks < 8; ++ks) {
    const int k0 = ks * 64;
    gload_lds16(asrc + k0 * 2, adst);
    #pragma unroll
    for (int it = 0; it < 8; ++it) {
      int c = it * 512 + tid;
      int bn = c >> 3;
      int bo = (c & 7) ^ (bn & 7);
      const char* bsrc = (const char*)(wf1T + (size_t)(n0 + bn) * 512 + k0) + bo * 16;
      gload_lds16(bsrc, (char*)Bs + it * 8192 + wave * 1024);
    }
    __syncthreads();
    #pragma unroll
    for (int kk = 0; kk < 2; ++kk) {
      const int d = kk * 4 + quad;          // 16B slot index in k-dim
      const int so = ((d ^ aswz) << 4);
      s8v a0 = *(const s8v*)((const char*)As + abase0 + so);
      s8v a1 = *(const s8v*)((const char*)As + abase1 + so);
      #pragma unroll
      for (int ct = 0; ct < 8; ++ct) {
        s8v b = *(const s8v*)((const char*)Bs + bbase + ct * 2048 + so);
        acc[0][ct] = MFMA16(a0, b, acc[0][ct], 0, 0, 0);
        acc[1][ct] = MFMA16(a1, b, acc[1][ct], 0, 0, 0);
      }
    }
    __syncthreads();
  }

  #pragma unroll
  for (int ct = 0; ct < 8; ++ct) {
    int col = n0 + cw * 128 + ct * 16 + l15;
    float bb = bf1[col];
    #pragma unroll
    for (int t = 0; t < 2; ++t)
      #pragma unroll
      for (int g = 0; g < 4; ++g) {
        size_t row = row0 + rw * 32 + t * 16 + quad * 4 + g;
        hid[row * 1024 + col] = f2bf(fmaxf(acc[t][ct][g] + bb, 0.f));
      }
  }
}

// ---------------------------------------------------------------------------
// K3b: refined = LN(h + hid@Wf2 + bf2; g2,be2)  fp32.
// hid aliases the refined buffer (block reads only its own rows as A before
// overwriting them in the epilogue -> block-local, safe).
// 64x512 tile (full N, so LN is block-local), K=1024 in 16 BK=64 steps.
// ---------------------------------------------------------------------------
__global__ __launch_bounds__(512, 4) void k3b_ffn2(
    const unsigned short* hid, const unsigned short* __restrict__ wf2T,
    const float* __restrict__ bf2, const unsigned short* __restrict__ h,
    const float* __restrict__ g2, const float* __restrict__ be2,
    float* refined) {
  __shared__ unsigned short As[64 * 64];   // 8 KB
  __shared__ unsigned short Bs[512 * 64];  // 64 KB
  __shared__ float rsum[64], rsq[64];
  const int tid = threadIdx.x;
  const int wave = tid >> 6, lane = tid & 63, quad = lane >> 4, l15 = lane & 15;
  const int rw = wave >> 2, cw = wave & 3;
  const size_t row0 = (size_t)blockIdx.x * 64;

  if (tid < 64) { rsum[tid] = 0.f; rsq[tid] = 0.f; }

  const int ar = tid >> 3;
  const int ao = (tid & 7) ^ (ar & 7);
  const char* asrc = (const char*)(hid + (row0 + ar) * 1024) + ao * 16;
  char* adst = (char*)As + (size_t)wave * 1024;

  const int aswz = (l15 & 7);
  const int abase0 = (rw * 32 + l15) * 128;
  const int abase1 = (rw * 32 + 16 + l15) * 128;
  const int bbase = (cw * 128 + l15) * 128;

  f4v acc[2][8] = {};
  for (int ks = 0; ks < 16; ++ks) {
    const int k0 = ks * 64;
    gload_lds16(asrc + k0 * 2, adst);
    #pragma unroll
    for (int it = 0; it < 8; ++it) {
      int c = it * 512 + tid;
      int bn = c >> 3;
      int bo = (c & 7) ^ (bn & 7);
      const char* bsrc = (const char*)(wf2T + (size_t)bn * 1024 + k0) + bo * 16;
      gload_lds16(bsrc, (char*)Bs + it * 8192 + wave * 1024);
    }
    __syncthreads();
    #pragma unroll
    for (int kk = 0; kk < 2; ++kk) {
      const int d = kk * 4 + quad;
      const int so = ((d ^ aswz) << 4);
      s8v a0 = *(const s8v*)((const char*)As + abase0 + so);
      s8v a1 = *(const s8v*)((const char*)As + abase1 + so);
      #pragma unroll
      for (int ct = 0; ct < 8; ++ct) {
        s8v b = *(const s8v*)((const char*)Bs + bbase + ct * 2048 + so);
        acc[0][ct] = MFMA16(a0, b, acc[0][ct], 0, 0, 0);
        acc[1][ct] = MFMA16(a1, b, acc[1][ct], 0, 0, 0);
      }
    }
    __syncthreads();
  }

  // epilogue: val = acc + bf2 + h(residual); row stats via in-quad shuffle +
  // cross-wave LDS atomics; then LN and fp32 store (overwrites hid rows).
  #pragma unroll
  for (int t = 0; t < 2; ++t)
    #pragma unroll
    for (int g = 0; g < 4; ++g) {
      int lrow = rw * 32 + t * 16 + quad * 4 + g;
      size_t row = row0 + lrow;
      float ps = 0.f, ps2 = 0.f;
      #pragma unroll
      for (int ct = 0; ct < 8; ++ct) {
        int col = cw * 128 + ct * 16 + l15;
        float v = acc[t][ct][g] + bf2[col] + bf2f(h[row * 512 + col]);
        acc[t][ct][g] = v;
        ps += v; ps2 += v * v;
      }
      #pragma unroll
      for (int o = 1; o < 16; o <<= 1) {
        ps += __shfl_xor(ps, o);
        ps2 += __shfl_xor(ps2, o);
      }
      if (l15 == 0) { atomicAdd(&rsum[lrow], ps); atomicAdd(&rsq[lrow], ps2); }
    }
  __syncthreads();

  #pragma unroll
  for (int t = 0; t < 2; ++t)
    #pragma unroll
    for (int g = 0; g < 4; ++g) {
      int lrow = rw * 32 + t * 16 + quad * 4 + g;
      size_t row = row0 + lrow;
      float mu = rsum[lrow] * (1.f / 512.f);
      float var = rsq[lrow] * (1.f / 512.f) - mu * mu;
      float rs = rsqrtf(var + 1e-5f);
      #pragma unroll
      for (int ct = 0; ct < 8; ++ct) {
        int col = cw * 128 + ct * 16 + l15;
        refined[row * 512 + col] = (acc[t][ct][g] - mu) * rs * g2[col] + be2[col];
      }
    }
}

// ---------------------------------------------------------------------------
// K4: score MLP + softmax pooling + final param-free LN -> fused, alpha
// ---------------------------------------------------------------------------
__global__ __launch_bounds__(512, 2) void k4_pool(
    const float* __restrict__ refined, const unsigned short* __restrict__ ws1T,
    const float* __restrict__ bs1, const float* __restrict__ ws2,
    const float* __restrict__ bs2, float* __restrict__ fused,
    float* __restrict__ alpha) {
  __shared__ unsigned short xs[64 * 520];
  __shared__ float sc[64];
  __shared__ float al[2][32];
  const int tid = threadIdx.x;
  const int wave = tid >> 6, lane = tid & 63, quad = lane >> 4, l15 = lane & 15;
  const int rw = wave >> 2, cw = wave & 3;
  const size_t row0 = (size_t)blockIdx.x * 64;

  if (tid < 64) sc[tid] = 0.f;
  STAGE64_F32(refined + row0 * 512);
  __syncthreads();

  f4v acc[2][8] = {};
  KLOOP_512(ws1T, 512);

  // per-row score partials: relu(acc+bs1[col]) * ws2[col]
  float ps[2][4] = {};
  #pragma unroll
  for (int t = 0; t < 2; ++t)
    #pragma unroll
    for (int ct = 0; ct < 8; ++ct) {
      int col = cw * 128 + ct * 16 + l15;
      float b1 = bs1[col], w2 = ws2[col];
      #pragma unroll
      for (int g = 0; g < 4; ++g) {
        float v = fmaxf(acc[t][ct][g] + b1, 0.f);
        ps[t][g] += v * w2;
      }
    }
  #pragma unroll
  for (int t = 0; t < 2; ++t)
    #pragma unroll
    for (int g = 0; g < 4; ++g) {
      int m = rw * 32 + t * 16 + quad * 4 + g;
      atomicAdd(&sc[m], ps[t][g]);
    }
  __syncthreads();

  if (tid < 32) {
    float s0 = sc[tid * 2 + 0] + bs2[0];
    float s1 = sc[tid * 2 + 1] + bs2[0];
    float mx = fmaxf(s0, s1);
    float e0 = expf(s0 - mx), e1 = expf(s1 - mx);
    float inv = 1.f / (e0 + e1);
    float a0 = e0 * inv, a1 = e1 * inv;
    al[0][tid] = a0; al[1][tid] = a1;
    size_t gb = (size_t)blockIdx.x * 32 + tid;
    alpha[gb * 2 + 0] = a0;
    alpha[gb * 2 + 1] = a1;
  }
  __syncthreads();

  for (int rr = 0; rr < 4; ++rr) {
    int fb = wave * 4 + rr;               // local batch 0..31
    float a0 = al[0][fb], a1 = al[1][fb];
    int c0 = lane * 8;
    float v[8]; float s = 0.f, s2 = 0.f;
    #pragma unroll
    for (int j = 0; j < 8; ++j) {
      int c = c0 + j;
      float val = a0 * bf2f(xs[(fb * 2) * 520 + c]) + a1 * bf2f(xs[(fb * 2 + 1) * 520 + c]);
      v[j] = val; s += val; s2 += val * val;
    }
    #pragma unroll
    for (int o = 32; o; o >>= 1) { s += __shfl_xor(s, o); s2 += __shfl_xor(s2, o); }
    float mu = s * (1.f / 512.f);
    float var = s2 * (1.f / 512.f) - mu * mu;
    float rs = rsqrtf(var + 1e-5f);
    size_t gb = (size_t)blockIdx.x * 32 + fb;
    float4 f0, f1;
    f0.x = (v[0] - mu) * rs; f0.y = (v[1] - mu) * rs;
    f0.z = (v[2] - mu) * rs; f0.w = (v[3] - mu) * rs;
    f1.x = (v[4] - mu) * rs; f1.y = (v[5] - mu) * rs;
    f1.z = (v[6] - mu) * rs; f1.w = (v[7] - mu) * rs;
    *(float4*)(fused + gb * 512 + c0) = f0;
    *(float4*)(fused + gb * 512 + c0 + 4) = f1;
  }
}

// ---------------------------------------------------------------------------
extern "C" void kernel_launch(void* const* d_in, const int* in_sizes, int n_in,
                              void* d_out, int out_size, void* d_ws, size_t ws_size,
                              hipStream_t stream) {
  const float* x   = (const float*)d_in[0];
  const float* wq  = (const float*)d_in[1];
  const float* bq  = (const float*)d_in[2];
  const float* wk  = (const float*)d_in[3];
  const float* bk  = (const float*)d_in[4];
  const float* wv  = (const float*)d_in[5];
  const float* bv  = (const float*)d_in[6];
  const float* wo  = (const float*)d_in[7];
  const float* bo  = (const float*)d_in[8];
  const float* g1  = (const float*)d_in[9];
  const float* be1 = (const float*)d_in[10];
  const float* wf1 = (const float*)d_in[11];
  const float* bf1 = (const float*)d_in[12];
  const float* wf2 = (const float*)d_in[13];
  const float* bf2 = (const float*)d_in[14];
  const float* g2  = (const float*)d_in[15];
  const float* be2 = (const float*)d_in[16];
  const float* ws1 = (const float*)d_in[17];
  const float* bs1 = (const float*)d_in[18];
  const float* ws2 = (const float*)d_in[19];
  const float* bs2 = (const float*)d_in[20];

  char* ws = (char*)d_ws;
  float*          attn = (float*)(ws);                                 // 1 MB
  unsigned short* gqk  = (unsigned short*)(ws + (1u << 20));           // 512 KB
  unsigned short* wvoT = (unsigned short*)(ws + (1u << 20) + 524288);  // 512 KB
  float*          woT  = (float*)(ws + (2u << 20));                    // 1 MB
  unsigned short* wf1T = (unsigned short*)(ws + (3u << 20));           // 1 MB
  unsigned short* wf2T = (unsigned short*)(ws + (4u << 20));           // 1 MB
  unsigned short* ws1T = (unsigned short*)(ws + (5u << 20));           // 512 KB
  float*          uvec = (float*)(ws + (5u << 20) + 524288);
  float*          wvec = uvec + 1024;
  float*          cvec = wvec + 1024;
  float*          bvo  = cvec + 1024;
  unsigned short* h    = (unsigned short*)(ws + (16u << 20));          // 128 MB

  float* fused_out   = (float*)d_out;
  float* alpha_out   = fused_out + (size_t)65536 * 512;
  float* refined_out = alpha_out + (size_t)65536 * 2;
  // hid (131072x1024 bf16, 256 MB) aliases refined_out (131072x512 fp32,
  // 256 MB): k3a fills it, k3b consumes its own rows then overwrites them.
  unsigned short* hid = (unsigned short*)refined_out;

  // --- weight prep ---
  tr32<<<dim3(1024), dim3(256), 0, stream>>>(wo, woT);
  nt_small<<<dim3(8, 8), dim3(256), 0, stream>>>(wq, wk, gqk);    // G = Wq Wk^T
  nt_small<<<dim3(8, 8), dim3(256), 0, stream>>>(woT, wv, wvoT);  // (Wv Wo)^T
  trcvt<<<dim3(2048), dim3(256), 0, stream>>>(wf1, wf1T, 512, 1024);
  trcvt<<<dim3(2048), dim3(256), 0, stream>>>(wf2, wf2T, 1024, 512);
  trcvt<<<dim3(1024), dim3(256), 0, stream>>>(ws1, ws1T, 512, 512);
  vecprep<<<dim3(4), dim3(512), 0, stream>>>(wq, wk, wo, bq, bk, bv, uvec, wvec, cvec, bvo);

  // --- main pipeline ---
  k1_attn<<<dim3(2048), dim3(512), 0, stream>>>(x, gqk, uvec, wvec, cvec, attn);
  k2_proj<<<dim3(2048), dim3(512), 0, stream>>>(x, wvoT, bvo, bo, attn, g1, be1, h);
  k3a_ffn1<<<dim3(2048, 2), dim3(512), 0, stream>>>(h, wf1T, bf1, hid);
  k3b_ffn2<<<dim3(2048), dim3(512), 0, stream>>>(hid, wf2T, bf2, h, g2, be2, refined_out);
  k4_pool<<<dim3(2048), dim3(512), 0, stream>>>(refined_out, ws1T, bs1, ws2, bs2,
                                                fused_out, alpha_out);
}

// Round 2
// 1842.379 us; speedup vs baseline: 1.6304x; 1.1985x over previous
//
#include <hip/hip_runtime.h>

// ---------------------------------------------------------------------------
// PRGAT fused transformer block on MI355X (gfx950), bf16 MFMA pipeline.
//
// Math restructuring (exact up to bf16 rounding):
//   G    = Wq @ Wk^T                    (512x512)
//   s[b,n,m] = x_n G x_m^T + x_n.(Wq bk) + (Wk bq).x_m + bq.bk
//   attn = softmax(leaky_relu(s/scale))
//   Wvo  = Wv @ Wo ; bvo = bv @ Wo
//   out  = attn @ (x@Wvo + bvo) + bo
//   h    = LN(x + out; g1,be1)                      [stored bf16 in ws]
//   hid  = relu(h@Wf1+bf1)                          [bf16, aliased in refined]
//   refined = LN(h + hid@Wf2 + bf2; g2,be2)         [fp32 to d_out]
//   score = relu(refined@Ws1+bs1)@ws2 + bs2 ; alpha = softmax_n
//   fused = LN_paramfree(sum_n alpha_n * refined_n)
// ---------------------------------------------------------------------------

typedef __attribute__((ext_vector_type(8))) short s8v;   // 8 x bf16 (4 VGPRs)
typedef __attribute__((ext_vector_type(4))) float f4v;   // MFMA accum

#define MFMA16 __builtin_amdgcn_mfma_f32_16x16x32_bf16

__device__ __forceinline__ unsigned short f2bf(float f) {
  union { float f; unsigned u; } v; v.f = f;
  unsigned u = v.u;
  unsigned r = (u + 0x7FFFu + ((u >> 16) & 1u)) >> 16;   // RNE
  return (unsigned short)r;
}
__device__ __forceinline__ float bf2f(unsigned short h) {
  union { unsigned u; float f; } v; v.u = ((unsigned)h) << 16;
  return v.f;
}

// async global->LDS, 16B per lane; lds dest = wave-uniform base + lane*16
__device__ __forceinline__ void gload_lds16(const void* g, void* l) {
  __builtin_amdgcn_global_load_lds(
      (const __attribute__((address_space(1))) unsigned int*)g,
      (__attribute__((address_space(3))) unsigned int*)l, 16, 0, 0);
}

// Stage 64 rows x 512 cols of fp32 -> bf16 into padded LDS [64][520].
#define STAGE64_F32(SRC) do { \
    const float4* sp_ = (const float4*)(SRC); \
    _Pragma("unroll") \
    for (int p_ = 0; p_ < 16; ++p_) { \
      int idx_ = p_ * 512 + tid; \
      int r_ = idx_ >> 7, c_ = (idx_ & 127) << 2; \
      float4 v_ = sp_[idx_]; \
      uint2 w_; \
      w_.x = (unsigned)f2bf(v_.x) | ((unsigned)f2bf(v_.y) << 16); \
      w_.y = (unsigned)f2bf(v_.z) | ((unsigned)f2bf(v_.w) << 16); \
      *(uint2*)(xs + r_ * 520 + c_) = w_; \
    } } while (0)

// ---------------------------------------------------------------------------
// Staged-B K-loop machinery (k1/k2/k4). A in xs[64][520] bf16 (padded).
// B bf16 [512 n][512 k] staged per BK=32 chunk into a 2x32KB LDS double
// buffer via global_load_lds (linear dest, pre-swizzled source); reads use
// the matching XOR: 16B slot = d ^ (n&3) ^ ((n>>2)&3).  One barrier/chunk;
// chunk ks+1 is prefetched while chunk ks is MFMA'd (T3 2-phase minimum).
// Per-kernel locals required: tid, wave, lane, quad, l15, rw, cw, acc, bsl,
// brow = tid>>2, boff = ((tid&3)^(brow&3)^((brow>>2)&3))<<4.
// ---------------------------------------------------------------------------
#define BSTAGE_CHUNK(BT, K0, DST) do { \
    _Pragma("unroll") \
    for (int it_ = 0; it_ < 4; ++it_) \
      gload_lds16((const char*)((BT) + (size_t)(it_ * 128 + brow) * 512 + (K0)) + boff, \
                  (DST) + (it_ * 512 + tid) * 16); \
  } while (0)

#define KLOOP_STAGED(BT) do { \
    const int ar0_ = (rw * 32 + l15) * 520, ar1_ = (rw * 32 + 16 + l15) * 520; \
    const int bsw_ = ((quad ^ (l15 & 3) ^ ((l15 >> 2) & 3)) << 4); \
    const int bro_ = (cw * 128 + l15) * 64; \
    for (int ks_ = 0; ks_ < 16; ++ks_) { \
      char* cur_ = bsl + (ks_ & 1) * 32768; \
      if (ks_ < 15) BSTAGE_CHUNK(BT, (ks_ + 1) * 32, bsl + ((ks_ & 1) ^ 1) * 32768); \
      int ka_ = ks_ * 32 + quad * 8; \
      s8v a0_ = *(const s8v*)(xs + ar0_ + ka_); \
      s8v a1_ = *(const s8v*)(xs + ar1_ + ka_); \
      _Pragma("unroll") \
      for (int ct_ = 0; ct_ < 8; ++ct_) { \
        s8v b_ = *(const s8v*)(cur_ + bro_ + ct_ * 1024 + bsw_); \
        acc[0][ct_] = MFMA16(a0_, b_, acc[0][ct_], 0, 0, 0); \
        acc[1][ct_] = MFMA16(a1_, b_, acc[1][ct_], 0, 0, 0); \
      } \
      __syncthreads(); \
    } \
  } while (0)

// ---------------------------------------------------------------------------
// Prep kernels (run every launch; ws is re-poisoned by harness)
// ---------------------------------------------------------------------------

// out[d*512+j] = in[j*512+d]  (fp32 512x512 transpose)
__global__ void tr32(const float* __restrict__ in, float* __restrict__ out) {
  int idx = blockIdx.x * 256 + threadIdx.x;
  int d = idx >> 9, j = idx & 511;
  out[idx] = in[j * 512 + d];
}

// C_bf16[i*512+j] = sum_d A[i*512+d] * B[j*512+d]   (512x512x512, NT)
__global__ void nt_small(const float* __restrict__ A, const float* __restrict__ B,
                         unsigned short* __restrict__ C) {
  __shared__ float As[64][68], Bs[64][68];
  int tx = threadIdx.x & 15, ty = threadIdx.x >> 4;
  int i0 = blockIdx.x * 64, j0 = blockIdx.y * 64;
  float acc[4][4] = {};
  for (int d0 = 0; d0 < 512; d0 += 64) {
    #pragma unroll
    for (int p = 0; p < 4; ++p) {
      int idx = p * 256 + threadIdx.x;       // 1024 float4 units
      int r = idx >> 4, c = (idx & 15) << 2;
      *(float4*)&As[r][c] = *(const float4*)&A[(i0 + r) * 512 + d0 + c];
      *(float4*)&Bs[r][c] = *(const float4*)&B[(j0 + r) * 512 + d0 + c];
    }
    __syncthreads();
    for (int dd = 0; dd < 64; ++dd) {
      float ar[4], br[4];
      #pragma unroll
      for (int r = 0; r < 4; ++r) ar[r] = As[ty * 4 + r][dd];
      #pragma unroll
      for (int c = 0; c < 4; ++c) br[c] = Bs[tx * 4 + c][dd];
      #pragma unroll
      for (int r = 0; r < 4; ++r)
        #pragma unroll
        for (int c = 0; c < 4; ++c) acc[r][c] += ar[r] * br[c];
    }
    __syncthreads();
  }
  #pragma unroll
  for (int r = 0; r < 4; ++r)
    #pragma unroll
    for (int c = 0; c < 4; ++c)
      C[(i0 + ty * 4 + r) * 512 + j0 + tx * 4 + c] = f2bf(acc[r][c]);
}

// out_bf16[n*K+k] = in[k*N+n]  (transpose + convert)
__global__ void trcvt(const float* __restrict__ in, unsigned short* __restrict__ out,
                      int K, int N) {
  int idx = blockIdx.x * 256 + threadIdx.x;
  if (idx >= K * N) return;
  int n = idx / K, k = idx - n * K;
  out[idx] = f2bf(in[(size_t)k * N + n]);
}

// u[i]=Wq[i,:].bk  w[j]=Wk[j,:].bq  bvo[d]=sum_j bv[j]Wo[j,d]  c=bq.bk
__global__ void vecprep(const float* __restrict__ wq, const float* __restrict__ wk,
                        const float* __restrict__ wo, const float* __restrict__ bq,
                        const float* __restrict__ bk, const float* __restrict__ bv,
                        float* __restrict__ uvec, float* __restrict__ wvec,
                        float* __restrict__ cvec, float* __restrict__ bvo) {
  int t = threadIdx.x;
  if (blockIdx.x == 0) {
    float s = 0.f; for (int d = 0; d < 512; ++d) s += wq[t * 512 + d] * bk[d];
    uvec[t] = s;
  } else if (blockIdx.x == 1) {
    float s = 0.f; for (int d = 0; d < 512; ++d) s += wk[t * 512 + d] * bq[d];
    wvec[t] = s;
  } else if (blockIdx.x == 2) {
    float s = 0.f; for (int j = 0; j < 512; ++j) s += bv[j] * wo[j * 512 + t];
    bvo[t] = s;
  } else {
    __shared__ float red[512];
    red[t] = bq[t] * bk[t];
    __syncthreads();
    for (int o = 256; o; o >>= 1) { if (t < o) red[t] += red[t + o]; __syncthreads(); }
    if (t == 0) cvec[0] = red[0];
  }
}

// ---------------------------------------------------------------------------
// K1: z = x @ G^T (never stored); epilogue computes attention weights.
// ---------------------------------------------------------------------------
__global__ __launch_bounds__(512, 2) void k1_attn(
    const float* __restrict__ x, const unsigned short* __restrict__ gqk,
    const float* __restrict__ uvec, const float* __restrict__ wvec,
    const float* __restrict__ cvec, float* __restrict__ attn) {
  __shared__ __align__(16) unsigned short xs[64 * 520];
  __shared__ __align__(16) char bsb[65536];       // Bs double buffer 2x32KB
  __shared__ float sbuf[32][2][2];
  __shared__ float rru[64];
  __shared__ float rrw[64];
  const int tid = threadIdx.x;
  const int wave = tid >> 6, lane = tid & 63, quad = lane >> 4, l15 = lane & 15;
  const int rw = wave >> 2, cw = wave & 3;
  const size_t row0 = (size_t)blockIdx.x * 64;
  char* bsl = bsb;
  const int brow = tid >> 2;
  const int boff = (((tid & 3) ^ (brow & 3) ^ ((brow >> 2) & 3)) << 4);

  if (tid < 128) ((float*)sbuf)[tid] = 0.f;
  else if (tid < 192) rru[tid - 128] = 0.f;
  else if (tid < 256) rrw[tid - 192] = 0.f;

  BSTAGE_CHUNK(gqk, 0, bsl);          // async prologue: chunk 0 -> buf0
  STAGE64_F32(x + row0 * 512);
  __syncthreads();

  // per-row bias dots: rru[r]=u.x_r  rrw[r]=w.x_r  (8 threads per row)
  {
    int row = tid >> 3, cb = (tid & 7) * 64;
    float su = 0.f, sw = 0.f;
    for (int c2 = 0; c2 < 64; ++c2) {
      float xv = bf2f(xs[row * 520 + cb + c2]);
      su += xv * uvec[cb + c2];
      sw += xv * wvec[cb + c2];
    }
    atomicAdd(&rru[row], su);
    atomicAdd(&rrw[row], sw);
  }

  f4v acc[2][8] = {};
  KLOOP_STAGED(gqk);

  // partial dots s[b,n,m] += x[2b+n,col] * z[2b+m,col] over this lane's cols
  float part[2][4][2] = {};
  #pragma unroll
  for (int t = 0; t < 2; ++t) {
    #pragma unroll
    for (int ct = 0; ct < 8; ++ct) {
      int col = cw * 128 + ct * 16 + l15;
      #pragma unroll
      for (int g = 0; g < 4; ++g) {
        int m = rw * 32 + t * 16 + quad * 4 + g;
        float zv = acc[t][ct][g];
        int b2 = m & ~1;
        part[t][g][0] += bf2f(xs[b2 * 520 + col]) * zv;
        part[t][g][1] += bf2f(xs[(b2 + 1) * 520 + col]) * zv;
      }
    }
  }
  #pragma unroll
  for (int t = 0; t < 2; ++t)
    #pragma unroll
    for (int g = 0; g < 4; ++g) {
      int m = rw * 32 + t * 16 + quad * 4 + g;
      atomicAdd(&sbuf[m >> 1][0][m & 1], part[t][g][0]);
      atomicAdd(&sbuf[m >> 1][1][m & 1], part[t][g][1]);
    }
  __syncthreads();

  if (tid < 64) {
    int bl = tid >> 1, nn = tid & 1;
    float cc = cvec[0];
    float ru = rru[bl * 2 + nn];
    float scale = sqrtf(512.f) + 1e-8f;
    float s0 = (sbuf[bl][nn][0] + ru + rrw[bl * 2 + 0] + cc) / scale;
    float s1 = (sbuf[bl][nn][1] + ru + rrw[bl * 2 + 1] + cc) / scale;
    s0 = s0 > 0.f ? s0 : 0.2f * s0;
    s1 = s1 > 0.f ? s1 : 0.2f * s1;
    float mx = fmaxf(s0, s1);
    float e0 = expf(s0 - mx), e1 = expf(s1 - mx);
    float inv = 1.f / (e0 + e1);
    size_t gb = (size_t)blockIdx.x * 32 + bl;
    attn[gb * 4 + nn * 2 + 0] = e0 * inv;
    attn[gb * 4 + nn * 2 + 1] = e1 * inv;
  }
}

// ---------------------------------------------------------------------------
// K2: vo = x@Wvo + bvo ; out = attn-mix(vo) + bo ; h = LN(x+out)  -> h bf16
// Bs double-buffer aliases the vos bounce buffer (Bs dead after K-loop).
// ---------------------------------------------------------------------------
__global__ __launch_bounds__(512, 2) void k2_proj(
    const float* __restrict__ x, const unsigned short* __restrict__ wvoT,
    const float* __restrict__ bvo, const float* __restrict__ bo,
    const float* __restrict__ attn, const float* __restrict__ g1,
    const float* __restrict__ be1, unsigned short* __restrict__ hout) {
  __shared__ __align__(16) unsigned short xs[64 * 520];
  __shared__ __align__(16) unsigned short bss[64 * 520];  // Bs dbuf, then vos
  const int tid = threadIdx.x;
  const int wave = tid >> 6, lane = tid & 63, quad = lane >> 4, l15 = lane & 15;
  const int rw = wave >> 2, cw = wave & 3;
  const size_t row0 = (size_t)blockIdx.x * 64;
  char* bsl = (char*)bss;
  unsigned short* vos = bss;
  const int brow = tid >> 2;
  const int boff = (((tid & 3) ^ (brow & 3) ^ ((brow >> 2) & 3)) << 4);

  BSTAGE_CHUNK(wvoT, 0, bsl);
  STAGE64_F32(x + row0 * 512);
  __syncthreads();

  f4v acc[2][8] = {};
  KLOOP_STAGED(wvoT);
  // K-loop's trailing barrier: all waves done with Bs -> safe to reuse as vos

  #pragma unroll
  for (int t = 0; t < 2; ++t)
    #pragma unroll
    for (int ct = 0; ct < 8; ++ct) {
      int col = cw * 128 + ct * 16 + l15;
      float bb = bvo[col];
      #pragma unroll
      for (int g = 0; g < 4; ++g) {
        int m = rw * 32 + t * 16 + quad * 4 + g;
        vos[m * 520 + col] = f2bf(acc[t][ct][g] + bb);
      }
    }
  __syncthreads();

  for (int rr = 0; rr < 8; ++rr) {
    int r = wave * 8 + rr;
    size_t grow = row0 + r;
    size_t gb = (size_t)blockIdx.x * 32 + (r >> 1);
    float a0 = attn[gb * 4 + (r & 1) * 2 + 0];
    float a1 = attn[gb * 4 + (r & 1) * 2 + 1];
    int c0 = lane * 8;
    int b2 = r & ~1;
    float v[8]; float s = 0.f, s2 = 0.f;
    #pragma unroll
    for (int j = 0; j < 8; ++j) {
      int c = c0 + j;
      float val = bf2f(xs[r * 520 + c]) + a0 * bf2f(vos[b2 * 520 + c]) +
                  a1 * bf2f(vos[(b2 + 1) * 520 + c]) + bo[c];
      v[j] = val; s += val; s2 += val * val;
    }
    #pragma unroll
    for (int o = 32; o; o >>= 1) { s += __shfl_xor(s, o); s2 += __shfl_xor(s2, o); }
    float mu = s * (1.f / 512.f);
    float var = s2 * (1.f / 512.f) - mu * mu;
    float rs = rsqrtf(var + 1e-5f);
    unsigned short o8[8];
    #pragma unroll
    for (int j = 0; j < 8; ++j)
      o8[j] = f2bf((v[j] - mu) * rs * g1[c0 + j] + be1[c0 + j]);
    int4 w4;
    w4.x = (int)((unsigned)o8[0] | ((unsigned)o8[1] << 16));
    w4.y = (int)((unsigned)o8[2] | ((unsigned)o8[3] << 16));
    w4.z = (int)((unsigned)o8[4] | ((unsigned)o8[5] << 16));
    w4.w = (int)((unsigned)o8[6] | ((unsigned)o8[7] << 16));
    *(int4*)(hout + grow * 512 + c0) = w4;
  }
}

// ---------------------------------------------------------------------------
// K3a: hid = relu(h @ Wf1 + bf1)  (bf16, stored into the refined buffer)
// m97-style staged GEMM: 64x512 tile, BK=64, global_load_lds + XOR swizzle.
// Block: 512 thr (8 waves, 2x4). Wave tile 32x128. LDS 72.5 KB -> 2 blk/CU.
// ---------------------------------------------------------------------------
__global__ __launch_bounds__(512, 4) void k3a_ffn1(
    const unsigned short* __restrict__ h, const unsigned short* __restrict__ wf1T,
    const float* __restrict__ bf1, unsigned short* __restrict__ hid) {
  __shared__ __align__(16) unsigned short As[64 * 64];   // 8 KB
  __shared__ __align__(16) unsigned short Bs[512 * 64];  // 64 KB
  const int tid = threadIdx.x;
  const int wave = tid >> 6, lane = tid & 63, quad = lane >> 4, l15 = lane & 15;
  const int rw = wave >> 2, cw = wave & 3;
  const size_t row0 = (size_t)blockIdx.x * 64;
  const int n0 = blockIdx.y * 512;

  const int ar = tid >> 3;
  const int ao = (tid & 7) ^ (ar & 7);
  const char* asrc = (const char*)(h + (row0 + ar) * 512) + ao * 16;
  char* adst = (char*)As + (size_t)wave * 1024;

  const int aswz = (l15 & 7);
  const int abase0 = (rw * 32 + l15) * 128;
  const int abase1 = (rw * 32 + 16 + l15) * 128;
  const int bbase = (cw * 128 + l15) * 128;

  f4v acc[2][8] = {};
  for (int ks = 0; ks < 8; ++ks) {
    const int k0 = ks * 64;
    gload_lds16(asrc + k0 * 2, adst);
    #pragma unroll
    for (int it = 0; it < 8; ++it) {
      int c = it * 512 + tid;
      int bn = c >> 3;
      int bo = (c & 7) ^ (bn & 7);
      const char* bsrc = (const char*)(wf1T + (size_t)(n0 + bn) * 512 + k0) + bo * 16;
      gload_lds16(bsrc, (char*)Bs + it * 8192 + wave * 1024);
    }
    __syncthreads();
    #pragma unroll
    for (int kk = 0; kk < 2; ++kk) {
      const int d = kk * 4 + quad;
      const int so = ((d ^ aswz) << 4);
      s8v a0 = *(const s8v*)((const char*)As + abase0 + so);
      s8v a1 = *(const s8v*)((const char*)As + abase1 + so);
      #pragma unroll
      for (int ct = 0; ct < 8; ++ct) {
        s8v b = *(const s8v*)((const char*)Bs + bbase + ct * 2048 + so);
        acc[0][ct] = MFMA16(a0, b, acc[0][ct], 0, 0, 0);
        acc[1][ct] = MFMA16(a1, b, acc[1][ct], 0, 0, 0);
      }
    }
    __syncthreads();
  }

  #pragma unroll
  for (int ct = 0; ct < 8; ++ct) {
    int col = n0 + cw * 128 + ct * 16 + l15;
    float bb = bf1[col];
    #pragma unroll
    for (int t = 0; t < 2; ++t)
      #pragma unroll
      for (int g = 0; g < 4; ++g) {
        size_t row = row0 + rw * 32 + t * 16 + quad * 4 + g;
        hid[row * 1024 + col] = f2bf(fmaxf(acc[t][ct][g] + bb, 0.f));
      }
  }
}

// ---------------------------------------------------------------------------
// K3b: refined = LN(h + hid@Wf2 + bf2; g2,be2)  fp32.
// hid aliases the refined buffer (block-local aliasing, safe).
// ---------------------------------------------------------------------------
__global__ __launch_bounds__(512, 4) void k3b_ffn2(
    const unsigned short* hid, const unsigned short* __restrict__ wf2T,
    const float* __restrict__ bf2, const unsigned short* __restrict__ h,
    const float* __restrict__ g2, const float* __restrict__ be2,
    float* refined) {
  __shared__ __align__(16) unsigned short As[64 * 64];   // 8 KB
  __shared__ __align__(16) unsigned short Bs[512 * 64];  // 64 KB
  __shared__ float rsum[64], rsq[64];
  const int tid = threadIdx.x;
  const int wave = tid >> 6, lane = tid & 63, quad = lane >> 4, l15 = lane & 15;
  const int rw = wave >> 2, cw = wave & 3;
  const size_t row0 = (size_t)blockIdx.x * 64;

  if (tid < 64) { rsum[tid] = 0.f; rsq[tid] = 0.f; }

  const int ar = tid >> 3;
  const int ao = (tid & 7) ^ (ar & 7);
  const char* asrc = (const char*)(hid + (row0 + ar) * 1024) + ao * 16;
  char* adst = (char*)As + (size_t)wave * 1024;

  const int aswz = (l15 & 7);
  const int abase0 = (rw * 32 + l15) * 128;
  const int abase1 = (rw * 32 + 16 + l15) * 128;
  const int bbase = (cw * 128 + l15) * 128;

  f4v acc[2][8] = {};
  for (int ks = 0; ks < 16; ++ks) {
    const int k0 = ks * 64;
    gload_lds16(asrc + k0 * 2, adst);
    #pragma unroll
    for (int it = 0; it < 8; ++it) {
      int c = it * 512 + tid;
      int bn = c >> 3;
      int bo = (c & 7) ^ (bn & 7);
      const char* bsrc = (const char*)(wf2T + (size_t)bn * 1024 + k0) + bo * 16;
      gload_lds16(bsrc, (char*)Bs + it * 8192 + wave * 1024);
    }
    __syncthreads();
    #pragma unroll
    for (int kk = 0; kk < 2; ++kk) {
      const int d = kk * 4 + quad;
      const int so = ((d ^ aswz) << 4);
      s8v a0 = *(const s8v*)((const char*)As + abase0 + so);
      s8v a1 = *(const s8v*)((const char*)As + abase1 + so);
      #pragma unroll
      for (int ct = 0; ct < 8; ++ct) {
        s8v b = *(const s8v*)((const char*)Bs + bbase + ct * 2048 + so);
        acc[0][ct] = MFMA16(a0, b, acc[0][ct], 0, 0, 0);
        acc[1][ct] = MFMA16(a1, b, acc[1][ct], 0, 0, 0);
      }
    }
    __syncthreads();
  }

  #pragma unroll
  for (int t = 0; t < 2; ++t)
    #pragma unroll
    for (int g = 0; g < 4; ++g) {
      int lrow = rw * 32 + t * 16 + quad * 4 + g;
      size_t row = row0 + lrow;
      float ps = 0.f, ps2 = 0.f;
      #pragma unroll
      for (int ct = 0; ct < 8; ++ct) {
        int col = cw * 128 + ct * 16 + l15;
        float v = acc[t][ct][g] + bf2[col] + bf2f(h[row * 512 + col]);
        acc[t][ct][g] = v;
        ps += v; ps2 += v * v;
      }
      #pragma unroll
      for (int o = 1; o < 16; o <<= 1) {
        ps += __shfl_xor(ps, o);
        ps2 += __shfl_xor(ps2, o);
      }
      if (l15 == 0) { atomicAdd(&rsum[lrow], ps); atomicAdd(&rsq[lrow], ps2); }
    }
  __syncthreads();

  #pragma unroll
  for (int t = 0; t < 2; ++t)
    #pragma unroll
    for (int g = 0; g < 4; ++g) {
      int lrow = rw * 32 + t * 16 + quad * 4 + g;
      size_t row = row0 + lrow;
      float mu = rsum[lrow] * (1.f / 512.f);
      float var = rsq[lrow] * (1.f / 512.f) - mu * mu;
      float rs = rsqrtf(var + 1e-5f);
      #pragma unroll
      for (int ct = 0; ct < 8; ++ct) {
        int col = cw * 128 + ct * 16 + l15;
        refined[row * 512 + col] = (acc[t][ct][g] - mu) * rs * g2[col] + be2[col];
      }
    }
}

// ---------------------------------------------------------------------------
// K4: score MLP + softmax pooling + final param-free LN -> fused, alpha
// ---------------------------------------------------------------------------
__global__ __launch_bounds__(512, 2) void k4_pool(
    const float* __restrict__ refined, const unsigned short* __restrict__ ws1T,
    const float* __restrict__ bs1, const float* __restrict__ ws2,
    const float* __restrict__ bs2, float* __restrict__ fused,
    float* __restrict__ alpha) {
  __shared__ __align__(16) unsigned short xs[64 * 520];
  __shared__ __align__(16) char bsb[65536];       // Bs double buffer 2x32KB
  __shared__ float sc[64];
  __shared__ float al[2][32];
  const int tid = threadIdx.x;
  const int wave = tid >> 6, lane = tid & 63, quad = lane >> 4, l15 = lane & 15;
  const int rw = wave >> 2, cw = wave & 3;
  const size_t row0 = (size_t)blockIdx.x * 64;
  char* bsl = bsb;
  const int brow = tid >> 2;
  const int boff = (((tid & 3) ^ (brow & 3) ^ ((brow >> 2) & 3)) << 4);

  if (tid < 64) sc[tid] = 0.f;
  BSTAGE_CHUNK(ws1T, 0, bsl);
  STAGE64_F32(refined + row0 * 512);
  __syncthreads();

  f4v acc[2][8] = {};
  KLOOP_STAGED(ws1T);

  // per-row score partials: relu(acc+bs1[col]) * ws2[col]
  float ps[2][4] = {};
  #pragma unroll
  for (int t = 0; t < 2; ++t)
    #pragma unroll
    for (int ct = 0; ct < 8; ++ct) {
      int col = cw * 128 + ct * 16 + l15;
      float b1 = bs1[col], w2 = ws2[col];
      #pragma unroll
      for (int g = 0; g < 4; ++g) {
        float v = fmaxf(acc[t][ct][g] + b1, 0.f);
        ps[t][g] += v * w2;
      }
    }
  #pragma unroll
  for (int t = 0; t < 2; ++t)
    #pragma unroll
    for (int g = 0; g < 4; ++g) {
      int m = rw * 32 + t * 16 + quad * 4 + g;
      atomicAdd(&sc[m], ps[t][g]);
    }
  __syncthreads();

  if (tid < 32) {
    float s0 = sc[tid * 2 + 0] + bs2[0];
    float s1 = sc[tid * 2 + 1] + bs2[0];
    float mx = fmaxf(s0, s1);
    float e0 = expf(s0 - mx), e1 = expf(s1 - mx);
    float inv = 1.f / (e0 + e1);
    float a0 = e0 * inv, a1 = e1 * inv;
    al[0][tid] = a0; al[1][tid] = a1;
    size_t gb = (size_t)blockIdx.x * 32 + tid;
    alpha[gb * 2 + 0] = a0;
    alpha[gb * 2 + 1] = a1;
  }
  __syncthreads();

  for (int rr = 0; rr < 4; ++rr) {
    int fb = wave * 4 + rr;               // local batch 0..31
    float a0 = al[0][fb], a1 = al[1][fb];
    int c0 = lane * 8;
    float v[8]; float s = 0.f, s2 = 0.f;
    #pragma unroll
    for (int j = 0; j < 8; ++j) {
      int c = c0 + j;
      float val = a0 * bf2f(xs[(fb * 2) * 520 + c]) + a1 * bf2f(xs[(fb * 2 + 1) * 520 + c]);
      v[j] = val; s += val; s2 += val * val;
    }
    #pragma unroll
    for (int o = 32; o; o >>= 1) { s += __shfl_xor(s, o); s2 += __shfl_xor(s2, o); }
    float mu = s * (1.f / 512.f);
    float var = s2 * (1.f / 512.f) - mu * mu;
    float rs = rsqrtf(var + 1e-5f);
    size_t gb = (size_t)blockIdx.x * 32 + fb;
    float4 f0, f1;
    f0.x = (v[0] - mu) * rs; f0.y = (v[1] - mu) * rs;
    f0.z = (v[2] - mu) * rs; f0.w = (v[3] - mu) * rs;
    f1.x = (v[4] - mu) * rs; f1.y = (v[5] - mu) * rs;
    f1.z = (v[6] - mu) * rs; f1.w = (v[7] - mu) * rs;
    *(float4*)(fused + gb * 512 + c0) = f0;
    *(float4*)(fused + gb * 512 + c0 + 4) = f1;
  }
}

// ---------------------------------------------------------------------------
extern "C" void kernel_launch(void* const* d_in, const int* in_sizes, int n_in,
                              void* d_out, int out_size, void* d_ws, size_t ws_size,
                              hipStream_t stream) {
  const float* x   = (const float*)d_in[0];
  const float* wq  = (const float*)d_in[1];
  const float* bq  = (const float*)d_in[2];
  const float* wk  = (const float*)d_in[3];
  const float* bk  = (const float*)d_in[4];
  const float* wv  = (const float*)d_in[5];
  const float* bv  = (const float*)d_in[6];
  const float* wo  = (const float*)d_in[7];
  const float* bo  = (const float*)d_in[8];
  const float* g1  = (const float*)d_in[9];
  const float* be1 = (const float*)d_in[10];
  const float* wf1 = (const float*)d_in[11];
  const float* bf1 = (const float*)d_in[12];
  const float* wf2 = (const float*)d_in[13];
  const float* bf2 = (const float*)d_in[14];
  const float* g2  = (const float*)d_in[15];
  const float* be2 = (const float*)d_in[16];
  const float* ws1 = (const float*)d_in[17];
  const float* bs1 = (const float*)d_in[18];
  const float* ws2 = (const float*)d_in[19];
  const float* bs2 = (const float*)d_in[20];

  char* ws = (char*)d_ws;
  float*          attn = (float*)(ws);                                 // 1 MB
  unsigned short* gqk  = (unsigned short*)(ws + (1u << 20));           // 512 KB
  unsigned short* wvoT = (unsigned short*)(ws + (1u << 20) + 524288);  // 512 KB
  float*          woT  = (float*)(ws + (2u << 20));                    // 1 MB
  unsigned short* wf1T = (unsigned short*)(ws + (3u << 20));           // 1 MB
  unsigned short* wf2T = (unsigned short*)(ws + (4u << 20));           // 1 MB
  unsigned short* ws1T = (unsigned short*)(ws + (5u << 20));           // 512 KB
  float*          uvec = (float*)(ws + (5u << 20) + 524288);
  float*          wvec = uvec + 1024;
  float*          cvec = wvec + 1024;
  float*          bvo  = cvec + 1024;
  unsigned short* h    = (unsigned short*)(ws + (16u << 20));          // 128 MB

  float* fused_out   = (float*)d_out;
  float* alpha_out   = fused_out + (size_t)65536 * 512;
  float* refined_out = alpha_out + (size_t)65536 * 2;
  // hid (131072x1024 bf16, 256 MB) aliases refined_out (131072x512 fp32,
  // 256 MB): k3a fills it, k3b consumes its own rows then overwrites them.
  unsigned short* hid = (unsigned short*)refined_out;

  // --- weight prep ---
  tr32<<<dim3(1024), dim3(256), 0, stream>>>(wo, woT);
  nt_small<<<dim3(8, 8), dim3(256), 0, stream>>>(wq, wk, gqk);    // G = Wq Wk^T
  nt_small<<<dim3(8, 8), dim3(256), 0, stream>>>(woT, wv, wvoT);  // (Wv Wo)^T
  trcvt<<<dim3(2048), dim3(256), 0, stream>>>(wf1, wf1T, 512, 1024);
  trcvt<<<dim3(2048), dim3(256), 0, stream>>>(wf2, wf2T, 1024, 512);
  trcvt<<<dim3(1024), dim3(256), 0, stream>>>(ws1, ws1T, 512, 512);
  vecprep<<<dim3(4), dim3(512), 0, stream>>>(wq, wk, wo, bq, bk, bv, uvec, wvec, cvec, bvo);

  // --- main pipeline ---
  k1_attn<<<dim3(2048), dim3(512), 0, stream>>>(x, gqk, uvec, wvec, cvec, attn);
  k2_proj<<<dim3(2048), dim3(512), 0, stream>>>(x, wvoT, bvo, bo, attn, g1, be1, h);
  k3a_ffn1<<<dim3(2048, 2), dim3(512), 0, stream>>>(h, wf1T, bf1, hid);
  k3b_ffn2<<<dim3(2048), dim3(512), 0, stream>>>(hid, wf2T, bf2, h, g2, be2, refined_out);
  k4_pool<<<dim3(2048), dim3(512), 0, stream>>>(refined_out, ws1T, bs1, ws2, bs2,
                                                fused_out, alpha_out);
}

// Round 3
// 1837.032 us; speedup vs baseline: 1.6352x; 1.0029x over previous
//
#include <hip/hip_runtime.h>

// ---------------------------------------------------------------------------
// PRGAT fused transformer block on MI355X (gfx950), bf16 MFMA pipeline.
//
// Math restructuring (exact up to bf16 rounding):
//   G    = Wq @ Wk^T                    (512x512)
//   s[b,n,m] = x_n G x_m^T + x_n.(Wq bk) + (Wk bq).x_m + bq.bk
//   attn = softmax(leaky_relu(s/scale))
//   Wvo  = Wv @ Wo ; bvo = bv @ Wo
//   out  = attn @ (x@Wvo + bvo) + bo
//   h    = LN(x + out; g1,be1)                      [stored bf16 in ws]
//   hid  = relu(h@Wf1+bf1)                          [bf16, aliased in refined]
//   refined = LN(h + hid@Wf2 + bf2; g2,be2)         [fp32 to d_out]
//   score = relu(refined@Ws1+bs1)@ws2 + bs2 ; alpha = softmax_n
//   fused = LN_paramfree(sum_n alpha_n * refined_n)
//
// All main GEMMs use the k3a skeleton: As[64][64] (8 KB) + Bs[512][64]
// (64 KB) staged per BK=64 chunk via global_load_lds with XOR-slot swizzle,
// 72.5 KB LDS -> 2 blocks/CU. Epilogues are in-register (row pairs live in
// the same lane) with shfl-first reductions.
// ---------------------------------------------------------------------------

typedef __attribute__((ext_vector_type(8))) short s8v;   // 8 x bf16 (4 VGPRs)
typedef __attribute__((ext_vector_type(4))) float f4v;   // MFMA accum

#define MFMA16 __builtin_amdgcn_mfma_f32_16x16x32_bf16

__device__ __forceinline__ unsigned short f2bf(float f) {
  union { float f; unsigned u; } v; v.f = f;
  unsigned u = v.u;
  unsigned r = (u + 0x7FFFu + ((u >> 16) & 1u)) >> 16;   // RNE
  return (unsigned short)r;
}
__device__ __forceinline__ float bf2f(unsigned short h) {
  union { unsigned u; float f; } v; v.u = ((unsigned)h) << 16;
  return v.f;
}

// async global->LDS, 16B per lane; lds dest = wave-uniform base + lane*16
__device__ __forceinline__ void gload_lds16(const void* g, void* l) {
  __builtin_amdgcn_global_load_lds(
      (const __attribute__((address_space(1))) unsigned int*)g,
      (__attribute__((address_space(3))) unsigned int*)l, 16, 0, 0);
}

// ---------------------------------------------------------------------------
// Staged GEMM core: C[64 x 512] = A[64 x K] @ B[512 x K]^T, K = NCHUNK*64.
// Requires locals: tid, wave, quad, l15, rw, cw, acc[2][8], As, Bs,
//   asrc (A row base incl. swizzled slot), adst, aswz, abase0/1, bbase.
// acc[t][ct][g] = C[rw*32 + t*16 + quad*4 + g][cw*128 + ct*16 + l15]
// ---------------------------------------------------------------------------
#define GEMM_CHUNKS(BBASE, LDB_ELT, NCHUNK) \
  for (int ks_ = 0; ks_ < (NCHUNK); ++ks_) { \
    const int k0_ = ks_ * 64; \
    gload_lds16(asrc + (size_t)k0_ * 2, adst); \
    _Pragma("unroll") \
    for (int it_ = 0; it_ < 8; ++it_) { \
      int c_ = it_ * 512 + tid; \
      int bn_ = c_ >> 3; \
      int bo_ = (c_ & 7) ^ (bn_ & 7); \
      gload_lds16((const char*)((BBASE) + (size_t)bn_ * (LDB_ELT) + k0_) + bo_ * 16, \
                  (char*)Bs + it_ * 8192 + wave * 1024); \
    } \
    __syncthreads(); \
    _Pragma("unroll") \
    for (int kk_ = 0; kk_ < 2; ++kk_) { \
      const int d_ = kk_ * 4 + quad; \
      const int so_ = ((d_ ^ aswz) << 4); \
      s8v a0_ = *(const s8v*)((const char*)As + abase0 + so_); \
      s8v a1_ = *(const s8v*)((const char*)As + abase1 + so_); \
      _Pragma("unroll") \
      for (int ct_ = 0; ct_ < 8; ++ct_) { \
        s8v b_ = *(const s8v*)((const char*)Bs + bbase + ct_ * 2048 + so_); \
        acc[0][ct_] = MFMA16(a0_, b_, acc[0][ct_], 0, 0, 0); \
        acc[1][ct_] = MFMA16(a1_, b_, acc[1][ct_], 0, 0, 0); \
      } \
    } \
    __syncthreads(); \
  }

#define GEMM_LOCALS(ASRC_BF, LDA_ELT) \
  const int ar_ = tid >> 3; \
  const int ao_ = (tid & 7) ^ (ar_ & 7); \
  const char* asrc = (const char*)((ASRC_BF) + (size_t)(row0 + ar_) * (LDA_ELT)) + ao_ * 16; \
  char* adst = (char*)As + (size_t)wave * 1024; \
  const int aswz = (l15 & 7); \
  const int abase0 = (rw * 32 + l15) * 128; \
  const int abase1 = (rw * 32 + 16 + l15) * 128; \
  const int bbase = (cw * 128 + l15) * 128;

// Stage the block's 64x512 bf16 tile into Bs (reusing the dead B buffer),
// slot-swizzled: LDS row r slot s holds global slot s^(r&7).
#define STAGE_XT(SRCBF) do { \
    _Pragma("unroll") \
    for (int it_ = 0; it_ < 8; ++it_) { \
      int c_ = it_ * 512 + tid; \
      int r_ = c_ >> 6, s_ = c_ & 63; \
      int sp_ = s_ ^ (r_ & 7); \
      gload_lds16((const char*)((SRCBF) + (size_t)(row0 + r_) * 512) + sp_ * 16, \
                  (char*)Bs + it_ * 8192 + wave * 1024); \
    } } while (0)

// element accessor for the XT tile (after barrier)
#define XT_AT(r, col) \
  bf2f(Bs[(r) * 512 + ((((col) >> 3) ^ ((r) & 7)) << 3) + ((col) & 7)])

// ---------------------------------------------------------------------------
// Prep kernels (run every launch; ws is re-poisoned by harness)
// ---------------------------------------------------------------------------

// x fp32 -> xbf bf16 (streaming)
__global__ __launch_bounds__(256) void cvt_bf(const float* __restrict__ x,
                                              unsigned short* __restrict__ xbf) {
  int idx = blockIdx.x * 256 + threadIdx.x;      // 524288 threads
  const float4* xp = (const float4*)x;
  uint2* op = (uint2*)xbf;
  #pragma unroll
  for (int p = 0; p < 32; ++p) {
    float4 v = xp[(size_t)p * 524288 + idx];
    uint2 w;
    w.x = (unsigned)f2bf(v.x) | ((unsigned)f2bf(v.y) << 16);
    w.y = (unsigned)f2bf(v.z) | ((unsigned)f2bf(v.w) << 16);
    op[(size_t)p * 524288 + idx] = w;
  }
}

// out[d*512+j] = in[j*512+d]  (fp32 512x512 transpose)
__global__ void tr32(const float* __restrict__ in, float* __restrict__ out) {
  int idx = blockIdx.x * 256 + threadIdx.x;
  int d = idx >> 9, j = idx & 511;
  out[idx] = in[j * 512 + d];
}

// C_bf16[i*512+j] = sum_d A[i*512+d] * B[j*512+d]   (512x512x512, NT)
__global__ void nt_small(const float* __restrict__ A, const float* __restrict__ B,
                         unsigned short* __restrict__ C) {
  __shared__ float As[64][68], Bs[64][68];
  int tx = threadIdx.x & 15, ty = threadIdx.x >> 4;
  int i0 = blockIdx.x * 64, j0 = blockIdx.y * 64;
  float acc[4][4] = {};
  for (int d0 = 0; d0 < 512; d0 += 64) {
    #pragma unroll
    for (int p = 0; p < 4; ++p) {
      int idx = p * 256 + threadIdx.x;       // 1024 float4 units
      int r = idx >> 4, c = (idx & 15) << 2;
      *(float4*)&As[r][c] = *(const float4*)&A[(i0 + r) * 512 + d0 + c];
      *(float4*)&Bs[r][c] = *(const float4*)&B[(j0 + r) * 512 + d0 + c];
    }
    __syncthreads();
    for (int dd = 0; dd < 64; ++dd) {
      float ar[4], br[4];
      #pragma unroll
      for (int r = 0; r < 4; ++r) ar[r] = As[ty * 4 + r][dd];
      #pragma unroll
      for (int c = 0; c < 4; ++c) br[c] = Bs[tx * 4 + c][dd];
      #pragma unroll
      for (int r = 0; r < 4; ++r)
        #pragma unroll
        for (int c = 0; c < 4; ++c) acc[r][c] += ar[r] * br[c];
    }
    __syncthreads();
  }
  #pragma unroll
  for (int r = 0; r < 4; ++r)
    #pragma unroll
    for (int c = 0; c < 4; ++c)
      C[(i0 + ty * 4 + r) * 512 + j0 + tx * 4 + c] = f2bf(acc[r][c]);
}

// out_bf16[n*K+k] = in[k*N+n]  (transpose + convert)
__global__ void trcvt(const float* __restrict__ in, unsigned short* __restrict__ out,
                      int K, int N) {
  int idx = blockIdx.x * 256 + threadIdx.x;
  if (idx >= K * N) return;
  int n = idx / K, k = idx - n * K;
  out[idx] = f2bf(in[(size_t)k * N + n]);
}

// u[i]=Wq[i,:].bk  w[j]=Wk[j,:].bq  bvo[d]=sum_j bv[j]Wo[j,d]  c=bq.bk
__global__ void vecprep(const float* __restrict__ wq, const float* __restrict__ wk,
                        const float* __restrict__ wo, const float* __restrict__ bq,
                        const float* __restrict__ bk, const float* __restrict__ bv,
                        float* __restrict__ uvec, float* __restrict__ wvec,
                        float* __restrict__ cvec, float* __restrict__ bvo) {
  int t = threadIdx.x;
  if (blockIdx.x == 0) {
    float s = 0.f; for (int d = 0; d < 512; ++d) s += wq[t * 512 + d] * bk[d];
    uvec[t] = s;
  } else if (blockIdx.x == 1) {
    float s = 0.f; for (int d = 0; d < 512; ++d) s += wk[t * 512 + d] * bq[d];
    wvec[t] = s;
  } else if (blockIdx.x == 2) {
    float s = 0.f; for (int j = 0; j < 512; ++j) s += bv[j] * wo[j * 512 + t];
    bvo[t] = s;
  } else {
    __shared__ float red[512];
    red[t] = bq[t] * bk[t];
    __syncthreads();
    for (int o = 256; o; o >>= 1) { if (t < o) red[t] += red[t + o]; __syncthreads(); }
    if (t == 0) cvec[0] = red[0];
  }
}

// ---------------------------------------------------------------------------
// K1: z = xbf @ G^T (in acc, never stored); epilogue -> attention weights.
// ---------------------------------------------------------------------------
__global__ __launch_bounds__(512, 4) void k1_attn(
    const unsigned short* __restrict__ xbf, const unsigned short* __restrict__ gqk,
    const float* __restrict__ uvec, const float* __restrict__ wvec,
    const float* __restrict__ cvec, float* __restrict__ attn) {
  __shared__ __align__(16) unsigned short As[64 * 64];   // 8 KB
  __shared__ __align__(16) unsigned short Bs[512 * 64];  // 64 KB (then XT)
  __shared__ float sbuf[32][2][2];
  __shared__ float rru[64];
  __shared__ float rrw[64];
  const int tid = threadIdx.x;
  const int wave = tid >> 6, lane = tid & 63, quad = lane >> 4, l15 = lane & 15;
  const int rw = wave >> 2, cw = wave & 3;
  const size_t row0 = (size_t)blockIdx.x * 64;

  if (tid < 128) ((float*)sbuf)[tid] = 0.f;
  else if (tid < 192) rru[tid - 128] = 0.f;
  else if (tid < 256) rrw[tid - 192] = 0.f;

  GEMM_LOCALS(xbf, 512);
  f4v acc[2][8] = {};
  GEMM_CHUNKS(gqk, 512, 8);

  // Bs dead -> stage x-tile for the epilogue
  STAGE_XT(xbf);
  __syncthreads();

  // per-row bias dots: rru[r]=u.x_r  rrw[r]=w.x_r  (8 threads per row)
  {
    int row = tid >> 3, cb = (tid & 7) * 64;
    float su = 0.f, sw = 0.f;
    for (int c2 = 0; c2 < 64; ++c2) {
      float xv = XT_AT(row, cb + c2);
      su += xv * uvec[cb + c2];
      sw += xv * wvec[cb + c2];
    }
    atomicAdd(&rru[row], su);
    atomicAdd(&rrw[row], sw);
  }

  // part[t][p][n][m'] = sum_cols x[2b+n][col] * z[2b+m'][col]
  // (rows 2b = base+2p and 2b+1 = base+2p+1 are acc g=2p, 2p+1 of this lane)
  float part[2][2][2][2] = {};
  #pragma unroll
  for (int t = 0; t < 2; ++t)
    #pragma unroll
    for (int ct = 0; ct < 8; ++ct) {
      int col = cw * 128 + ct * 16 + l15;
      #pragma unroll
      for (int p = 0; p < 2; ++p) {
        int b2 = rw * 32 + t * 16 + quad * 4 + 2 * p;
        float x0 = XT_AT(b2, col);
        float x1 = XT_AT(b2 + 1, col);
        float z0 = acc[t][ct][2 * p + 0];
        float z1 = acc[t][ct][2 * p + 1];
        part[t][p][0][0] += x0 * z0;
        part[t][p][0][1] += x0 * z1;
        part[t][p][1][0] += x1 * z0;
        part[t][p][1][1] += x1 * z1;
      }
    }
  // reduce over the 16 l15 lanes (same rows), then one atomic per value
  #pragma unroll
  for (int t = 0; t < 2; ++t)
    #pragma unroll
    for (int p = 0; p < 2; ++p)
      #pragma unroll
      for (int n = 0; n < 2; ++n)
        #pragma unroll
        for (int m = 0; m < 2; ++m) {
          float v = part[t][p][n][m];
          v += __shfl_xor(v, 1); v += __shfl_xor(v, 2);
          v += __shfl_xor(v, 4); v += __shfl_xor(v, 8);
          if (l15 == 0) {
            int b = (rw * 32 + t * 16 + quad * 4 + 2 * p) >> 1;
            atomicAdd(&sbuf[b][n][m], v);
          }
        }
  __syncthreads();

  if (tid < 64) {
    int bl = tid >> 1, nn = tid & 1;
    float cc = cvec[0];
    float ru = rru[bl * 2 + nn];
    float scale = sqrtf(512.f) + 1e-8f;
    float s0 = (sbuf[bl][nn][0] + ru + rrw[bl * 2 + 0] + cc) / scale;
    float s1 = (sbuf[bl][nn][1] + ru + rrw[bl * 2 + 1] + cc) / scale;
    s0 = s0 > 0.f ? s0 : 0.2f * s0;
    s1 = s1 > 0.f ? s1 : 0.2f * s1;
    float mx = fmaxf(s0, s1);
    float e0 = expf(s0 - mx), e1 = expf(s1 - mx);
    float inv = 1.f / (e0 + e1);
    size_t gb = (size_t)blockIdx.x * 32 + bl;
    attn[gb * 4 + nn * 2 + 0] = e0 * inv;
    attn[gb * 4 + nn * 2 + 1] = e1 * inv;
  }
}

// ---------------------------------------------------------------------------
// K2: vo = xbf@Wvo + bvo ; out = attn-mix(vo) + bo ; h = LN(x+out) -> h bf16
// attn-mix is in-register (row pairs live in the same lane, g=2p/2p+1).
// ---------------------------------------------------------------------------
__global__ __launch_bounds__(512, 4) void k2_proj(
    const unsigned short* __restrict__ xbf, const unsigned short* __restrict__ wvoT,
    const float* __restrict__ bvo, const float* __restrict__ bo,
    const float* __restrict__ attn, const float* __restrict__ g1,
    const float* __restrict__ be1, unsigned short* __restrict__ hout) {
  __shared__ __align__(16) unsigned short As[64 * 64];   // 8 KB
  __shared__ __align__(16) unsigned short Bs[512 * 64];  // 64 KB (then XT)
  __shared__ float rsum[64], rsq[64];
  const int tid = threadIdx.x;
  const int wave = tid >> 6, lane = tid & 63, quad = lane >> 4, l15 = lane & 15;
  const int rw = wave >> 2, cw = wave & 3;
  const size_t row0 = (size_t)blockIdx.x * 64;

  if (tid < 64) { rsum[tid] = 0.f; rsq[tid] = 0.f; }

  GEMM_LOCALS(xbf, 512);
  f4v acc[2][8] = {};
  GEMM_CHUNKS(wvoT, 512, 8);

  STAGE_XT(xbf);
  __syncthreads();

  // pass1: val = mix + x + bo (overwrites acc), accumulate row stats
  float ps[2][4] = {}, ps2[2][4] = {};
  #pragma unroll
  for (int t = 0; t < 2; ++t)
    #pragma unroll
    for (int p = 0; p < 2; ++p) {
      int b2 = rw * 32 + t * 16 + quad * 4 + 2 * p;
      size_t gb = (size_t)blockIdx.x * 32 + (b2 >> 1);
      float a00 = attn[gb * 4 + 0], a01 = attn[gb * 4 + 1];
      float a10 = attn[gb * 4 + 2], a11 = attn[gb * 4 + 3];
      #pragma unroll
      for (int ct = 0; ct < 8; ++ct) {
        int col = cw * 128 + ct * 16 + l15;
        float bvoc = bvo[col], boc = bo[col];
        float voA = acc[t][ct][2 * p + 0] + bvoc;
        float voB = acc[t][ct][2 * p + 1] + bvoc;
        float v0 = a00 * voA + a01 * voB + XT_AT(b2, col) + boc;
        float v1 = a10 * voA + a11 * voB + XT_AT(b2 + 1, col) + boc;
        acc[t][ct][2 * p + 0] = v0;
        acc[t][ct][2 * p + 1] = v1;
        ps[t][2 * p + 0] += v0; ps2[t][2 * p + 0] += v0 * v0;
        ps[t][2 * p + 1] += v1; ps2[t][2 * p + 1] += v1 * v1;
      }
    }
  #pragma unroll
  for (int t = 0; t < 2; ++t)
    #pragma unroll
    for (int g = 0; g < 4; ++g) {
      float s = ps[t][g], s2 = ps2[t][g];
      s += __shfl_xor(s, 1); s += __shfl_xor(s, 2);
      s += __shfl_xor(s, 4); s += __shfl_xor(s, 8);
      s2 += __shfl_xor(s2, 1); s2 += __shfl_xor(s2, 2);
      s2 += __shfl_xor(s2, 4); s2 += __shfl_xor(s2, 8);
      if (l15 == 0) {
        int lrow = rw * 32 + t * 16 + quad * 4 + g;
        atomicAdd(&rsum[lrow], s);
        atomicAdd(&rsq[lrow], s2);
      }
    }
  __syncthreads();

  // pass2: LN, write bf16 back into XT (swizzled, in-place over x values)
  #pragma unroll
  for (int t = 0; t < 2; ++t)
    #pragma unroll
    for (int g = 0; g < 4; ++g) {
      int lrow = rw * 32 + t * 16 + quad * 4 + g;
      float mu = rsum[lrow] * (1.f / 512.f);
      float var = rsq[lrow] * (1.f / 512.f) - mu * mu;
      float rs = rsqrtf(var + 1e-5f);
      #pragma unroll
      for (int ct = 0; ct < 8; ++ct) {
        int col = cw * 128 + ct * 16 + l15;
        float hv = (acc[t][ct][g] - mu) * rs * g1[col] + be1[col];
        Bs[lrow * 512 + (((col >> 3) ^ (lrow & 7)) << 3) + (col & 7)] = f2bf(hv);
      }
    }
  __syncthreads();

  // coalesced copy XT -> h (undo the slot swizzle on the LDS-read side)
  #pragma unroll
  for (int it = 0; it < 8; ++it) {
    int c = it * 512 + tid;
    int r = c >> 6, s = c & 63;
    int sp = s ^ (r & 7);
    *(int4*)(hout + (row0 + r) * 512 + s * 8) = *(const int4*)(Bs + r * 512 + sp * 8);
  }
}

// ---------------------------------------------------------------------------
// K3a: hid = relu(h @ Wf1 + bf1)  (bf16, stored into the refined buffer)
// ---------------------------------------------------------------------------
__global__ __launch_bounds__(512, 4) void k3a_ffn1(
    const unsigned short* __restrict__ h, const unsigned short* __restrict__ wf1T,
    const float* __restrict__ bf1, unsigned short* __restrict__ hid) {
  __shared__ __align__(16) unsigned short As[64 * 64];   // 8 KB
  __shared__ __align__(16) unsigned short Bs[512 * 64];  // 64 KB
  const int tid = threadIdx.x;
  const int wave = tid >> 6, lane = tid & 63, quad = lane >> 4, l15 = lane & 15;
  const int rw = wave >> 2, cw = wave & 3;
  const size_t row0 = (size_t)blockIdx.x * 64;
  const int n0 = blockIdx.y * 512;

  GEMM_LOCALS(h, 512);
  const unsigned short* wb = wf1T + (size_t)n0 * 512;
  f4v acc[2][8] = {};
  GEMM_CHUNKS(wb, 512, 8);

  #pragma unroll
  for (int ct = 0; ct < 8; ++ct) {
    int col = n0 + cw * 128 + ct * 16 + l15;
    float bb = bf1[col];
    #pragma unroll
    for (int t = 0; t < 2; ++t)
      #pragma unroll
      for (int g = 0; g < 4; ++g) {
        size_t row = row0 + rw * 32 + t * 16 + quad * 4 + g;
        hid[row * 1024 + col] = f2bf(fmaxf(acc[t][ct][g] + bb, 0.f));
      }
  }
}

// ---------------------------------------------------------------------------
// K3b: refined = LN(h + hid@Wf2 + bf2; g2,be2)  fp32 + bf16 copy (over h).
// hid aliases the refined buffer (block-local aliasing, safe).
// ---------------------------------------------------------------------------
__global__ __launch_bounds__(512, 4) void k3b_ffn2(
    const unsigned short* hid, const unsigned short* __restrict__ wf2T,
    const float* __restrict__ bf2, unsigned short* h,
    const float* __restrict__ g2, const float* __restrict__ be2,
    float* refined) {
  __shared__ __align__(16) unsigned short As[64 * 64];   // 8 KB
  __shared__ __align__(16) unsigned short Bs[512 * 64];  // 64 KB
  __shared__ float rsum[64], rsq[64];
  const int tid = threadIdx.x;
  const int wave = tid >> 6, lane = tid & 63, quad = lane >> 4, l15 = lane & 15;
  const int rw = wave >> 2, cw = wave & 3;
  const size_t row0 = (size_t)blockIdx.x * 64;

  if (tid < 64) { rsum[tid] = 0.f; rsq[tid] = 0.f; }

  GEMM_LOCALS(hid, 1024);
  f4v acc[2][8] = {};
  GEMM_CHUNKS(wf2T, 1024, 16);

  #pragma unroll
  for (int t = 0; t < 2; ++t)
    #pragma unroll
    for (int g = 0; g < 4; ++g) {
      int lrow = rw * 32 + t * 16 + quad * 4 + g;
      size_t row = row0 + lrow;
      float ps = 0.f, ps2 = 0.f;
      #pragma unroll
      for (int ct = 0; ct < 8; ++ct) {
        int col = cw * 128 + ct * 16 + l15;
        float v = acc[t][ct][g] + bf2[col] + bf2f(h[row * 512 + col]);
        acc[t][ct][g] = v;
        ps += v; ps2 += v * v;
      }
      #pragma unroll
      for (int o = 1; o < 16; o <<= 1) {
        ps += __shfl_xor(ps, o);
        ps2 += __shfl_xor(ps2, o);
      }
      if (l15 == 0) { atomicAdd(&rsum[lrow], ps); atomicAdd(&rsq[lrow], ps2); }
    }
  __syncthreads();

  #pragma unroll
  for (int t = 0; t < 2; ++t)
    #pragma unroll
    for (int g = 0; g < 4; ++g) {
      int lrow = rw * 32 + t * 16 + quad * 4 + g;
      size_t row = row0 + lrow;
      float mu = rsum[lrow] * (1.f / 512.f);
      float var = rsq[lrow] * (1.f / 512.f) - mu * mu;
      float rs = rsqrtf(var + 1e-5f);
      #pragma unroll
      for (int ct = 0; ct < 8; ++ct) {
        int col = cw * 128 + ct * 16 + l15;
        float rv = (acc[t][ct][g] - mu) * rs * g2[col] + be2[col];
        refined[row * 512 + col] = rv;
        h[row * 512 + col] = f2bf(rv);     // bf16 copy for k4 (h is dead)
      }
    }
}

// ---------------------------------------------------------------------------
// K4: score MLP + softmax pooling + final param-free LN -> fused, alpha
// ---------------------------------------------------------------------------
__global__ __launch_bounds__(512, 4) void k4_pool(
    const unsigned short* __restrict__ refbf, const unsigned short* __restrict__ ws1T,
    const float* __restrict__ bs1, const float* __restrict__ ws2,
    const float* __restrict__ bs2, float* __restrict__ fused,
    float* __restrict__ alpha) {
  __shared__ __align__(16) unsigned short As[64 * 64];   // 8 KB
  __shared__ __align__(16) unsigned short Bs[512 * 64];  // 64 KB (then XT)
  __shared__ float sc[64];
  __shared__ float al[2][32];
  const int tid = threadIdx.x;
  const int wave = tid >> 6, lane = tid & 63, quad = lane >> 4, l15 = lane & 15;
  const int rw = wave >> 2, cw = wave & 3;
  const size_t row0 = (size_t)blockIdx.x * 64;

  if (tid < 64) sc[tid] = 0.f;

  GEMM_LOCALS(refbf, 512);
  f4v acc[2][8] = {};
  GEMM_CHUNKS(ws1T, 512, 8);

  // per-row score partials: relu(acc+bs1[col]) * ws2[col]
  float ps[2][4] = {};
  #pragma unroll
  for (int t = 0; t < 2; ++t)
    #pragma unroll
    for (int ct = 0; ct < 8; ++ct) {
      int col = cw * 128 + ct * 16 + l15;
      float b1 = bs1[col], w2 = ws2[col];
      #pragma unroll
      for (int g = 0; g < 4; ++g) {
        float v = fmaxf(acc[t][ct][g] + b1, 0.f);
        ps[t][g] += v * w2;
      }
    }

  STAGE_XT(refbf);          // issue refined-tile staging; drained by barrier

  #pragma unroll
  for (int t = 0; t < 2; ++t)
    #pragma unroll
    for (int g = 0; g < 4; ++g) {
      float v = ps[t][g];
      v += __shfl_xor(v, 1); v += __shfl_xor(v, 2);
      v += __shfl_xor(v, 4); v += __shfl_xor(v, 8);
      if (l15 == 0) {
        int m = rw * 32 + t * 16 + quad * 4 + g;
        atomicAdd(&sc[m], v);
      }
    }
  __syncthreads();

  if (tid < 32) {
    float s0 = sc[tid * 2 + 0] + bs2[0];
    float s1 = sc[tid * 2 + 1] + bs2[0];
    float mx = fmaxf(s0, s1);
    float e0 = expf(s0 - mx), e1 = expf(s1 - mx);
    float inv = 1.f / (e0 + e1);
    float a0 = e0 * inv, a1 = e1 * inv;
    al[0][tid] = a0; al[1][tid] = a1;
    size_t gb = (size_t)blockIdx.x * 32 + tid;
    alpha[gb * 2 + 0] = a0;
    alpha[gb * 2 + 1] = a1;
  }
  __syncthreads();

  for (int rr = 0; rr < 4; ++rr) {
    int fb = wave * 4 + rr;               // local batch 0..31
    float a0 = al[0][fb], a1 = al[1][fb];
    int r0 = fb * 2, r1 = fb * 2 + 1;
    s8v v0 = *(const s8v*)(Bs + r0 * 512 + ((lane ^ (r0 & 7)) << 3));
    s8v v1 = *(const s8v*)(Bs + r1 * 512 + ((lane ^ (r1 & 7)) << 3));
    float v[8]; float s = 0.f, s2 = 0.f;
    #pragma unroll
    for (int j = 0; j < 8; ++j) {
      float val = a0 * bf2f((unsigned short)v0[j]) + a1 * bf2f((unsigned short)v1[j]);
      v[j] = val; s += val; s2 += val * val;
    }
    #pragma unroll
    for (int o = 32; o; o >>= 1) { s += __shfl_xor(s, o); s2 += __shfl_xor(s2, o); }
    float mu = s * (1.f / 512.f);
    float var = s2 * (1.f / 512.f) - mu * mu;
    float rs = rsqrtf(var + 1e-5f);
    size_t gb = (size_t)blockIdx.x * 32 + fb;
    int c0 = lane * 8;
    float4 f0, f1;
    f0.x = (v[0] - mu) * rs; f0.y = (v[1] - mu) * rs;
    f0.z = (v[2] - mu) * rs; f0.w = (v[3] - mu) * rs;
    f1.x = (v[4] - mu) * rs; f1.y = (v[5] - mu) * rs;
    f1.z = (v[6] - mu) * rs; f1.w = (v[7] - mu) * rs;
    *(float4*)(fused + gb * 512 + c0) = f0;
    *(float4*)(fused + gb * 512 + c0 + 4) = f1;
  }
}

// ---------------------------------------------------------------------------
extern "C" void kernel_launch(void* const* d_in, const int* in_sizes, int n_in,
                              void* d_out, int out_size, void* d_ws, size_t ws_size,
                              hipStream_t stream) {
  const float* x   = (const float*)d_in[0];
  const float* wq  = (const float*)d_in[1];
  const float* bq  = (const float*)d_in[2];
  const float* wk  = (const float*)d_in[3];
  const float* bk  = (const float*)d_in[4];
  const float* wv  = (const float*)d_in[5];
  const float* bv  = (const float*)d_in[6];
  const float* wo  = (const float*)d_in[7];
  const float* bo  = (const float*)d_in[8];
  const float* g1  = (const float*)d_in[9];
  const float* be1 = (const float*)d_in[10];
  const float* wf1 = (const float*)d_in[11];
  const float* bf1 = (const float*)d_in[12];
  const float* wf2 = (const float*)d_in[13];
  const float* bf2 = (const float*)d_in[14];
  const float* g2  = (const float*)d_in[15];
  const float* be2 = (const float*)d_in[16];
  const float* ws1 = (const float*)d_in[17];
  const float* bs1 = (const float*)d_in[18];
  const float* ws2 = (const float*)d_in[19];
  const float* bs2 = (const float*)d_in[20];

  char* ws = (char*)d_ws;
  float*          attn = (float*)(ws);                                 // 1 MB
  unsigned short* gqk  = (unsigned short*)(ws + (1u << 20));           // 512 KB
  unsigned short* wvoT = (unsigned short*)(ws + (1u << 20) + 524288);  // 512 KB
  float*          woT  = (float*)(ws + (2u << 20));                    // 1 MB
  unsigned short* wf1T = (unsigned short*)(ws + (3u << 20));           // 1 MB
  unsigned short* wf2T = (unsigned short*)(ws + (4u << 20));           // 1 MB
  unsigned short* ws1T = (unsigned short*)(ws + (5u << 20));           // 512 KB
  float*          uvec = (float*)(ws + (5u << 20) + 524288);
  float*          wvec = uvec + 1024;
  float*          cvec = wvec + 1024;
  float*          bvo  = cvec + 1024;
  unsigned short* h    = (unsigned short*)(ws + (16u << 20));          // 128 MB

  float* fused_out   = (float*)d_out;
  float* alpha_out   = fused_out + (size_t)65536 * 512;
  float* refined_out = alpha_out + (size_t)65536 * 2;
  // hid (131072x1024 bf16, 256 MB) aliases refined_out (131072x512 fp32).
  unsigned short* hid = (unsigned short*)refined_out;
  // xbf (131072x512 bf16, 128 MB) aliases fused_out (65536x512 fp32, 128 MB):
  // written by cvt_bf, consumed by k1/k2, dead before k4 writes fused.
  unsigned short* xbf = (unsigned short*)fused_out;
  // refined bf16 copy overwrites h in-place in k3b (h dead after k3b).
  unsigned short* refbf = h;

  // --- weight prep ---
  tr32<<<dim3(1024), dim3(256), 0, stream>>>(wo, woT);
  nt_small<<<dim3(8, 8), dim3(256), 0, stream>>>(wq, wk, gqk);    // G = Wq Wk^T
  nt_small<<<dim3(8, 8), dim3(256), 0, stream>>>(woT, wv, wvoT);  // (Wv Wo)^T
  trcvt<<<dim3(2048), dim3(256), 0, stream>>>(wf1, wf1T, 512, 1024);
  trcvt<<<dim3(2048), dim3(256), 0, stream>>>(wf2, wf2T, 1024, 512);
  trcvt<<<dim3(1024), dim3(256), 0, stream>>>(ws1, ws1T, 512, 512);
  vecprep<<<dim3(4), dim3(512), 0, stream>>>(wq, wk, wo, bq, bk, bv, uvec, wvec, cvec, bvo);
  cvt_bf<<<dim3(2048), dim3(256), 0, stream>>>(x, xbf);

  // --- main pipeline ---
  k1_attn<<<dim3(2048), dim3(512), 0, stream>>>(xbf, gqk, uvec, wvec, cvec, attn);
  k2_proj<<<dim3(2048), dim3(512), 0, stream>>>(xbf, wvoT, bvo, bo, attn, g1, be1, h);
  k3a_ffn1<<<dim3(2048, 2), dim3(512), 0, stream>>>(h, wf1T, bf1, hid);
  k3b_ffn2<<<dim3(2048), dim3(512), 0, stream>>>(hid, wf2T, bf2, h, g2, be2, refined_out);
  k4_pool<<<dim3(2048), dim3(512), 0, stream>>>(refbf, ws1T, bs1, ws2, bs2,
                                                fused_out, alpha_out);
}